// Round 9
// baseline (680.893 us; speedup 1.0000x reference)
//
#include <hip/hip_runtime.h>
#include <hip/hip_fp16.h>

#define IN_DIM 128
#define NCLS 40

// ---------------- degree / norm ----------------

__global__ __launch_bounds__(256) void deg_kernel(const int* __restrict__ src, const int* __restrict__ dst,
                                                  int* __restrict__ ds, int* __restrict__ dd, int E) {
    int e = blockIdx.x * 256 + threadIdx.x;
    if (e < E) {
        atomicAdd(&ds[src[e]], 1);
        atomicAdd(&dd[dst[e]], 1);
    }
}

__global__ __launch_bounds__(256) void norm_kernel(const int* __restrict__ ds, const int* __restrict__ dd,
                                                   float* __restrict__ ns, float* __restrict__ nd, int N) {
    int i = blockIdx.x * 256 + threadIdx.x;
    if (i < N) {
        ns[i] = ds[i] > 0 ? rsqrtf((float)ds[i]) : 0.f;
        nd[i] = dd[i] > 0 ? rsqrtf((float)dd[i]) : 0.f;
    }
}

// ---------------- exclusive scan of in-degrees -> row_ptr ----------------

__global__ __launch_bounds__(256) void scan_partial(const int* __restrict__ dd, int* __restrict__ bsums, int N) {
    __shared__ int sd[256];
    int t = threadIdx.x;
    int base = blockIdx.x * 1024 + t * 4;
    int s = 0;
#pragma unroll
    for (int k = 0; k < 4; ++k) { int i = base + k; if (i < N) s += dd[i]; }
    sd[t] = s;
    __syncthreads();
    for (int off = 128; off > 0; off >>= 1) {
        if (t < off) sd[t] += sd[t + off];
        __syncthreads();
    }
    if (t == 0) bsums[blockIdx.x] = sd[0];
}

// one block, 128 threads, LDS Hillis-Steele with carry chunks
__global__ __launch_bounds__(128) void scan_bsums(int* __restrict__ bsums, int nb) {
    __shared__ int sd[128];
    __shared__ int carry_s;
    int t = threadIdx.x;
    if (t == 0) carry_s = 0;
    __syncthreads();
    for (int base = 0; base < nb; base += 128) {
        int i = base + t;
        int orig = (i < nb) ? bsums[i] : 0;
        sd[t] = orig;
        __syncthreads();
        for (int off = 1; off < 128; off <<= 1) {
            int u = (t >= off) ? sd[t - off] : 0;
            __syncthreads();
            sd[t] += u;
            __syncthreads();
        }
        int carry = carry_s;
        if (i < nb) bsums[i] = carry + sd[t] - orig;   // exclusive
        __syncthreads();
        if (t == 127) carry_s = carry + sd[127];
        __syncthreads();
    }
}

__global__ __launch_bounds__(256) void scan_final(const int* __restrict__ dd, const int* __restrict__ bsums,
                                                  int* __restrict__ cursor, int N) {
    __shared__ int sd[256];
    int t = threadIdx.x;
    int base = blockIdx.x * 1024 + t * 4;
    int v[4]; int s = 0;
#pragma unroll
    for (int k = 0; k < 4; ++k) { int i = base + k; v[k] = (i < N) ? dd[i] : 0; s += v[k]; }
    sd[t] = s;
    __syncthreads();
    for (int off = 1; off < 256; off <<= 1) {
        int u = (t >= off) ? sd[t - off] : 0;
        __syncthreads();
        sd[t] += u;
        __syncthreads();
    }
    int excl = sd[t] - s + bsums[blockIdx.x];
#pragma unroll
    for (int k = 0; k < 4; ++k) {
        int i = base + k;
        if (i < N) cursor[i] = excl;
        excl += v[k];
    }
}

__global__ __launch_bounds__(256) void fill_csr(const int* __restrict__ src, const int* __restrict__ dst,
                                                int* __restrict__ cursor, int* __restrict__ csr, int E) {
    int e = blockIdx.x * 256 + threadIdx.x;
    if (e < E) {
        int slot = atomicAdd(&cursor[dst[e]], 1);
        csr[slot] = src[e];
    }
}

// ---------------- helpers ----------------

__device__ __forceinline__ float4 zero4() { return make_float4(0.f, 0.f, 0.f, 0.f); }

__device__ __forceinline__ void fma4(float4& acc, float s, const float4& wv) {
    acc.x = fmaf(s, wv.x, acc.x);
    acc.y = fmaf(s, wv.y, acc.y);
    acc.z = fmaf(s, wv.z, acc.z);
    acc.w = fmaf(s, wv.w, acc.w);
}

// accumulate 8 halves (one int4) into two float4s
__device__ __forceinline__ void add_h8(float4& a0, float4& a1, const int4& v) {
    const __half2* h = (const __half2*)&v;
    float2 f0 = __half22float2(h[0]);
    float2 f1 = __half22float2(h[1]);
    float2 f2 = __half22float2(h[2]);
    float2 f3 = __half22float2(h[3]);
    a0.x += f0.x; a0.y += f0.y; a0.z += f1.x; a0.w += f1.y;
    a1.x += f2.x; a1.y += f2.y; a1.z += f3.x; a1.w += f3.y;
}

__device__ __forceinline__ int4 pack_h8(const float4& o0, const float4& o1) {
    int4 p;
    __half2* ph = (__half2*)&p;
    ph[0] = __float22half2_rn(make_float2(o0.x, o0.y));
    ph[1] = __float22half2_rn(make_float2(o0.z, o0.w));
    ph[2] = __float22half2_rn(make_float2(o1.x, o1.y));
    ph[3] = __float22half2_rn(make_float2(o1.z, o1.w));
    return p;
}

// ---------------- prescale: xh[i] = fp16(x[i] * ns[row]) ----------------

__global__ __launch_bounds__(256) void prescale_kernel(const float* __restrict__ x, const float* __restrict__ ns,
                                                       __half* __restrict__ xh, int N) {
    int tid = blockIdx.x * 256 + threadIdx.x;     // one per 8 floats
    if (tid >= N * 16) return;
    int row = tid >> 4;
    int c = tid & 15;
    float s = ns[row];
    const float4* xp = (const float4*)x + (size_t)row * 32 + c * 2;
    float4 v0 = xp[0], v1 = xp[1];
    v0.x *= s; v0.y *= s; v0.z *= s; v0.w *= s;
    v1.x *= s; v1.y *= s; v1.z *= s; v1.w *= s;
    ((int4*)xh)[tid] = pack_h8(v0, v1);
}

// ---------------- fused gather(fp16) + GEMM layer, slot-based CSR walk ----------------
// block = 32 dst rows, 256 threads. Gather: 16 slots (4 waves x 4 groups), each slot
// walks a contiguous 1/16 of the block's CSR range with independent iterations;
// register accumulate per row-run, LDS atomicAdd flush on row change. c=lane&15 owns
// 8 halves (int4) of the feature row. GEMM: thread = 2 rows x 8 cols, As fp32 from LDS,
// W fp32 from L2, epilogue acc*nd + bias, relu, (*ns), fp16 out.

template<int SCALE_NS>
__global__ __launch_bounds__(256, 8) void fused_layer(const __half* __restrict__ xh, const int* __restrict__ csr,
                                                      const int* __restrict__ cursor, const float* __restrict__ ns,
                                                      const float* __restrict__ nd, const float* __restrict__ W,
                                                      const float* __restrict__ bias, __half* __restrict__ out, int N) {
    __shared__ float As[32 * 132];   // 16.9 KB
    __shared__ int rp[33];
    int t = threadIdx.x;
    int row0 = blockIdx.x * 32;

    if (t <= 32) {
        int r = row0 + t;
        rp[t] = (r == 0) ? 0 : cursor[min(r, N) - 1];
    }
    {
        float4* Az = (float4*)As;
        for (int i = t; i < 32 * 33; i += 256) Az[i] = zero4();
    }
    __syncthreads();

    int lane = t & 63;
    int wv = t >> 6;
    int g = lane >> 4;       // group 0..3
    int c = lane & 15;       // chunk: halves [c*8, c*8+8)
    int slot = wv * 4 + g;   // 0..15
    int estart = rp[0], eend = rp[32];
    int eblk = eend - estart;
    int len = (eblk + 15) >> 4;
    int e0 = estart + slot * len;
    int e1 = min(e0 + len, eend);
    const int4* xi = (const int4*)xh;

    if (e0 < e1) {
        // cur = max r with rp[r] <= e0 (5-step binary search, wave-uniform per group)
        int lo = 0, hi = 32;
        while (hi - lo > 1) { int mid = (lo + hi) >> 1; if (rp[mid] <= e0) lo = mid; else hi = mid; }
        int cur = lo;
        int nxt = rp[cur + 1];
        float4 a0 = zero4(), a1 = zero4();
#pragma unroll 4
        for (int e = e0; e < e1; ++e) {
            while (e >= nxt) {
                float* dp = &As[cur * 132 + c * 8];
                atomicAdd(dp + 0, a0.x); atomicAdd(dp + 1, a0.y);
                atomicAdd(dp + 2, a0.z); atomicAdd(dp + 3, a0.w);
                atomicAdd(dp + 4, a1.x); atomicAdd(dp + 5, a1.y);
                atomicAdd(dp + 6, a1.z); atomicAdd(dp + 7, a1.w);
                a0 = zero4(); a1 = zero4();
                ++cur; nxt = rp[cur + 1];
            }
            int idx = csr[e];
            int4 v = xi[(size_t)idx * 16 + c];
            add_h8(a0, a1, v);
        }
        float* dp = &As[cur * 132 + c * 8];
        atomicAdd(dp + 0, a0.x); atomicAdd(dp + 1, a0.y);
        atomicAdd(dp + 2, a0.z); atomicAdd(dp + 3, a0.w);
        atomicAdd(dp + 4, a1.x); atomicAdd(dp + 5, a1.y);
        atomicAdd(dp + 6, a1.z); atomicAdd(dp + 7, a1.w);
    }
    __syncthreads();

    // ---- GEMM phase: thread = 2 rows x 8 cols ----
    int rg = t >> 4;          // 0..15 -> rows rg*2, rg*2+1
    int cgp = t & 15;         // col float4s cgp*2, cgp*2+1
    int rbase = rg * 2;
    const float4* Wg = (const float4*)W;
    float4 acc[2][2];
    acc[0][0] = zero4(); acc[0][1] = zero4();
    acc[1][0] = zero4(); acc[1][1] = zero4();
#pragma unroll 2
    for (int k4 = 0; k4 < 32; ++k4) {
        int k0 = k4 * 4;
        float4 a[2];
        a[0] = *(const float4*)&As[(rbase + 0) * 132 + k0];
        a[1] = *(const float4*)&As[(rbase + 1) * 132 + k0];
        float4 w[4][2];
#pragma unroll
        for (int j = 0; j < 4; ++j) {
            w[j][0] = Wg[(k0 + j) * 32 + cgp * 2 + 0];
            w[j][1] = Wg[(k0 + j) * 32 + cgp * 2 + 1];
        }
#pragma unroll
        for (int m = 0; m < 2; ++m) {
            fma4(acc[m][0], a[m].x, w[0][0]); fma4(acc[m][1], a[m].x, w[0][1]);
            fma4(acc[m][0], a[m].y, w[1][0]); fma4(acc[m][1], a[m].y, w[1][1]);
            fma4(acc[m][0], a[m].z, w[2][0]); fma4(acc[m][1], a[m].z, w[2][1]);
            fma4(acc[m][0], a[m].w, w[3][0]); fma4(acc[m][1], a[m].w, w[3][1]);
        }
    }

    float4 bb0 = ((const float4*)bias)[cgp * 2 + 0];
    float4 bb1 = ((const float4*)bias)[cgp * 2 + 1];
#pragma unroll
    for (int m = 0; m < 2; ++m) {
        int gr = row0 + rbase + m;
        if (gr < N) {
            float ndr = nd[gr];
            float4 o0, o1;
            o0.x = fmaxf(fmaf(acc[m][0].x, ndr, bb0.x), 0.f);
            o0.y = fmaxf(fmaf(acc[m][0].y, ndr, bb0.y), 0.f);
            o0.z = fmaxf(fmaf(acc[m][0].z, ndr, bb0.z), 0.f);
            o0.w = fmaxf(fmaf(acc[m][0].w, ndr, bb0.w), 0.f);
            o1.x = fmaxf(fmaf(acc[m][1].x, ndr, bb1.x), 0.f);
            o1.y = fmaxf(fmaf(acc[m][1].y, ndr, bb1.y), 0.f);
            o1.z = fmaxf(fmaf(acc[m][1].z, ndr, bb1.z), 0.f);
            o1.w = fmaxf(fmaf(acc[m][1].w, ndr, bb1.w), 0.f);
            if (SCALE_NS) {
                float s = ns[gr];
                o0.x *= s; o0.y *= s; o0.z *= s; o0.w *= s;
                o1.x *= s; o1.y *= s; o1.z *= s; o1.w *= s;
            }
            ((int4*)out)[(size_t)gr * 16 + cgp] = pack_h8(o0, o1);
        }
    }
}

// ---------------- GEMM 128(fp16) -> 40, epilogue *ns -> fp16 y (stride 40 halves) ----------

__global__ __launch_bounds__(256) void gemm40_kernel(const __half* __restrict__ A, const float* __restrict__ W,
                                                     const float* __restrict__ ns, __half* __restrict__ y, int N) {
    __shared__ float Ws[128 * NCLS];   // 20 KB
    __shared__ float As[32 * 132];     // 16.5 KB
    int t = threadIdx.x;
    int row0 = blockIdx.x * 32;

#pragma unroll
    for (int i = 0; i < 5; ++i) {
        int idx = t + 256 * i;
        ((float4*)Ws)[idx] = ((const float4*)W)[idx];
    }
#pragma unroll
    for (int i = 0; i < 2; ++i) {
        int idx = t + 256 * i;        // 0..511
        int r = idx >> 4;
        int c16 = idx & 15;
        int gr = row0 + r;
        int4 v = make_int4(0, 0, 0, 0);
        if (gr < N) v = ((const int4*)A)[(size_t)gr * 16 + c16];
        const __half2* h = (const __half2*)&v;
        float2 f0 = __half22float2(h[0]);
        float2 f1 = __half22float2(h[1]);
        float2 f2 = __half22float2(h[2]);
        float2 f3 = __half22float2(h[3]);
        float* dp = &As[r * 132 + c16 * 8];
        dp[0] = f0.x; dp[1] = f0.y; dp[2] = f1.x; dp[3] = f1.y;
        dp[4] = f2.x; dp[5] = f2.y; dp[6] = f3.x; dp[7] = f3.y;
    }
    __syncthreads();

    int row = t >> 3;
    int cg = t & 7;
    float acc[5] = {0.f, 0.f, 0.f, 0.f, 0.f};
#pragma unroll 2
    for (int k4 = 0; k4 < 32; ++k4) {
        float4 a = *(const float4*)&As[row * 132 + k4 * 4];
#pragma unroll
        for (int j = 0; j < 4; ++j) {
            float av = (j == 0) ? a.x : (j == 1) ? a.y : (j == 2) ? a.z : a.w;
            const float* wp = &Ws[(k4 * 4 + j) * NCLS + cg * 5];
            acc[0] = fmaf(av, wp[0], acc[0]);
            acc[1] = fmaf(av, wp[1], acc[1]);
            acc[2] = fmaf(av, wp[2], acc[2]);
            acc[3] = fmaf(av, wp[3], acc[3]);
            acc[4] = fmaf(av, wp[4], acc[4]);
        }
    }
    int gr = row0 + row;
    if (gr < N) {
        float s = ns[gr];
        __half* yp = y + (size_t)gr * NCLS + cg * 5;
        yp[0] = __float2half_rn(acc[0] * s);
        yp[1] = __float2half_rn(acc[1] * s);
        yp[2] = __float2half_rn(acc[2] * s);
        yp[3] = __float2half_rn(acc[3] * s);
        yp[4] = __float2half_rn(acc[4] * s);
    }
}

// ---------------- gather 40-d, slot-based + fused *nd + b2 -> out (fp32) ----------------
// block = 32 rows, 32 slots (4 waves x 8 groups), c=lane&7 (<5 active, 8 halves each).

__global__ __launch_bounds__(256, 8) void gather40_finish(const __half* __restrict__ y, const int* __restrict__ csr,
                                                          const int* __restrict__ cursor, const float* __restrict__ nd,
                                                          const float* __restrict__ b2, float* __restrict__ out, int N) {
    __shared__ float As[32 * 44];   // 5.6 KB
    __shared__ int rp[33];
    int t = threadIdx.x;
    int row0 = blockIdx.x * 32;

    if (t <= 32) {
        int r = row0 + t;
        rp[t] = (r == 0) ? 0 : cursor[min(r, N) - 1];
    }
    for (int i = t; i < 32 * 44; i += 256) As[i] = 0.f;
    __syncthreads();

    int lane = t & 63;
    int wv = t >> 6;
    int g = lane >> 3;       // group 0..7
    int c = lane & 7;        // chunk (active c<5): halves [c*8, c*8+8)
    int slot = wv * 8 + g;   // 0..31
    int estart = rp[0], eend = rp[32];
    int eblk = eend - estart;
    int len = (eblk + 31) >> 5;
    int e0 = estart + slot * len;
    int e1 = min(e0 + len, eend);
    const int4* yi = (const int4*)y;

    if (e0 < e1) {
        int lo = 0, hi = 32;
        while (hi - lo > 1) { int mid = (lo + hi) >> 1; if (rp[mid] <= e0) lo = mid; else hi = mid; }
        int cur = lo;
        int nxt = rp[cur + 1];
        float4 a0 = zero4(), a1 = zero4();
#pragma unroll 4
        for (int e = e0; e < e1; ++e) {
            while (e >= nxt) {
                if (c < 5) {
                    float* dp = &As[cur * 44 + c * 8];
                    atomicAdd(dp + 0, a0.x); atomicAdd(dp + 1, a0.y);
                    atomicAdd(dp + 2, a0.z); atomicAdd(dp + 3, a0.w);
                    atomicAdd(dp + 4, a1.x); atomicAdd(dp + 5, a1.y);
                    atomicAdd(dp + 6, a1.z); atomicAdd(dp + 7, a1.w);
                }
                a0 = zero4(); a1 = zero4();
                ++cur; nxt = rp[cur + 1];
            }
            if (c < 5) {
                int idx = csr[e];
                int4 v = yi[(size_t)idx * 5 + c];
                add_h8(a0, a1, v);
            }
        }
        if (c < 5) {
            float* dp = &As[cur * 44 + c * 8];
            atomicAdd(dp + 0, a0.x); atomicAdd(dp + 1, a0.y);
            atomicAdd(dp + 2, a0.z); atomicAdd(dp + 3, a0.w);
            atomicAdd(dp + 4, a1.x); atomicAdd(dp + 5, a1.y);
            atomicAdd(dp + 6, a1.z); atomicAdd(dp + 7, a1.w);
        }
    }
    __syncthreads();

    // epilogue: out[r][k] = As[r][k] * nd[r] + b2[k]
    for (int i = t; i < 32 * NCLS; i += 256) {
        int r = i / NCLS;
        int k = i - r * NCLS;
        int gr = row0 + r;
        if (gr < N) out[(size_t)gr * NCLS + k] = fmaf(As[r * 44 + k], nd[gr], b2[k]);
    }
}

extern "C" void kernel_launch(void* const* d_in, const int* in_sizes, int n_in,
                              void* d_out, int out_size, void* d_ws, size_t ws_size,
                              hipStream_t stream) {
    const float* x  = (const float*)d_in[0];
    const int* src  = (const int*)d_in[1];
    const int* dst  = (const int*)d_in[2];
    const float* W0 = (const float*)d_in[3];
    const float* b0 = (const float*)d_in[4];
    const float* W1 = (const float*)d_in[5];
    const float* b1 = (const float*)d_in[6];
    const float* W2 = (const float*)d_in[7];
    const float* b2 = (const float*)d_in[8];
    float* out = (float*)d_out;

    int N = in_sizes[0] / IN_DIM;
    int E = in_sizes[1];

    float* base = (float*)d_ws;
    float* ns   = base;                       // N
    float* ndn  = base + (size_t)N;           // N
    int* dsg    = (int*)(base + 2 * (size_t)N);
    int* ddg    = (int*)(base + 3 * (size_t)N);
    int* cursor = (int*)(base + 4 * (size_t)N);
    int* bsums  = (int*)(base + 5 * (size_t)N);          // 1024
    int* csr    = (int*)(base + 5 * (size_t)N + 1024);   // E
    __half* xh  = (__half*)(csr + (size_t)E);            // N x 128 halves
    __half* h0  = xh + (size_t)N * 128;                  // N x 128 halves
    __half* h1  = h0 + (size_t)N * 128;                  // N x 128 halves
    __half* yh  = h1 + (size_t)N * 128;                  // N x 40 halves

    int nb = (N + 1023) / 1024;

    (void)hipMemsetAsync(dsg, 0, 2 * (size_t)N * sizeof(int), stream);
    deg_kernel<<<(E + 255) / 256, 256, 0, stream>>>(src, dst, dsg, ddg, E);
    norm_kernel<<<(N + 255) / 256, 256, 0, stream>>>(dsg, ddg, ns, ndn, N);

    scan_partial<<<nb, 256, 0, stream>>>(ddg, bsums, N);
    scan_bsums<<<1, 128, 0, stream>>>(bsums, nb);
    scan_final<<<nb, 256, 0, stream>>>(ddg, bsums, cursor, N);
    fill_csr<<<(E + 255) / 256, 256, 0, stream>>>(src, dst, cursor, csr, E);

    // xh = fp16(x * ns)
    prescale_kernel<<<(N * 16 + 255) / 256, 256, 0, stream>>>(x, ns, xh, N);

    int gblk32 = (N + 31) / 32;

    // layer 0: gather(xh) -> (*nd in epilogue) @W0+b0 -> relu -> *ns -> fp16 h0
    fused_layer<1><<<gblk32, 256, 0, stream>>>(xh, csr, cursor, ns, ndn, W0, b0, h0, N);
    // layer 1: gather(h0) -> @W1+b1 -> relu -> fp16 h1
    fused_layer<0><<<gblk32, 256, 0, stream>>>(h0, csr, cursor, ns, ndn, W1, b1, h1, N);
    // layer 2: y = (h1 @ W2) * ns (fp16, stride 40) -> gather40 -> *nd + b2
    gemm40_kernel<<<gblk32, 256, 0, stream>>>(h1, W2, ns, yh, N);
    gather40_finish<<<gblk32, 256, 0, stream>>>(yh, csr, cursor, ndn, b2, out, N);
}